// Round 1
// 274.274 us; speedup vs baseline: 1.0438x; 1.0438x over previous
//
#include <hip/hip_runtime.h>
#include <math.h>

#define POOL 7
#define NCELL 49
#define NCH 256
#define CH_SPLIT 8            // 8000 blocks; 32 ch/block, 8 ch/wave
#define CHPB (NCH / CH_SPLIT)
#define CHPW (CHPB / 4)
#define LDSF 640              // floats per wave window buffer (window packed <= ~601)
#define NIT 10                // staging iters: 10*64 = 640

// Async staging: per-lane global gather -> LDS (dest = uniform base + lane*4),
// which matches the packed layout sm[k*64+lane] exactly. No VGPR data regs,
// no ds_write, and the loads for channel i+1 stay in flight (counted vmcnt)
// while channel i is consumed from the other LDS buffer.
typedef __attribute__((address_space(1))) void global_void;
typedef __attribute__((address_space(3))) void lds_void;
__device__ __forceinline__ void async_stage(const float* g, float* l) {
    __builtin_amdgcn_global_load_lds((global_void*)g, (lds_void*)l, 4, 0, 0);
}

// One block per (channel-slice, box). grid(8, N): linear id = c + 8*n, so
// XCD = id % 8 = c (round-robin heuristic) -> each channel slice's cross-box
// window overlap stays in ONE XCD's L2 (~9 MB working set vs 4 MB L2) instead
// of being smeared across all 8 and only caught by the MALL.
__global__ __launch_bounds__(256, 8) void roi_align_fpn_kernel(
    const float* __restrict__ p2, const float* __restrict__ p3,
    const float* __restrict__ p4, const float* __restrict__ p5,
    const float* __restrict__ boxes, const int* __restrict__ bidx,
    float* __restrict__ out, int N)
{
    __shared__ float smem[4][2][LDSF];   // 20480 B -> 8 blocks/CU (= thread cap)
    const int n = blockIdx.y;
    const int t = threadIdx.x;
    const int wave = t >> 6;
    const int lane = t & 63;

    // ---- per-box params (block-uniform) ----
    float bx1 = boxes[4 * n + 0], by1 = boxes[4 * n + 1];
    float bx2 = boxes[4 * n + 2], by2 = boxes[4 * n + 3];
    float area = (by2 - by1) * (bx2 - bx1);
    float lvlf = logf(sqrtf(area)) * 1.4426950408889634f; // log2(sqrt(area))
    int level = (int)fminf(fmaxf(rintf(lvlf) + 4.0f, 0.0f), 3.0f);
    int W = 256 >> level;        // square levels
    int HW = W * W;
    float scale = (float)W;
    float x1 = bx1 * scale, y1 = by1 * scale;
    float bin_w = fmaxf((bx2 - bx1) * scale, 1.0f) * (1.0f / POOL);
    float bin_h = fmaxf((by2 - by1) * scale, 1.0f) * (1.0f / POOL);

    const float* feat = (level == 0) ? p2 : (level == 1) ? p3 : (level == 2) ? p4 : p5;
    feat += (size_t)bidx[n] * NCH * HW;

    // ---- window bounds (block-uniform; samples are monotonic in py/px) ----
    float yA = y1 + bin_h * 0.25f, yB = y1 + bin_h * 6.75f;
    float xA = x1 + bin_w * 0.25f, xB = x1 + bin_w * 6.75f;
    int y0  = (int)floorf(fminf(fmaxf(yA, 0.f), (float)(W - 1)));
    int y1h = min((int)floorf(fminf(fmaxf(yB, 0.f), (float)(W - 1))) + 1, W - 1);
    int x0  = (int)floorf(fminf(fmaxf(xA, 0.f), (float)(W - 1)));
    x0 = min(x0, W - 2);                       // pair base can be one left of first xlo
    int x1p = min((int)floorf(fminf(fmaxf(xB, 0.f), (float)(W - 1))) + 1, W - 1);
    int ww = x1p - x0 + 1;
    int wh = y1h - y0 + 1;
    wh = min(wh, LDSF / ww);                   // provably a no-op; memory-safety clamp
    int packed = ww * wh;

    // ---- staging address table (per lane, reused for all channels) ----
    int g_off[NIT];
#pragma unroll
    for (int k = 0; k < NIT; ++k) {
        int idx = k * 64 + lane;
        idx = (idx < packed) ? idx : 0;        // spare slots duplicate elem 0 (1 extra line)
        int r = idx / ww;
        int c = idx - r * ww;
        g_off[k] = (y0 + r) * W + (x0 + c);
    }

    const int ch0 = blockIdx.x * CHPB + wave * CHPW;
    const float* fbase = feat + (size_t)ch0 * HW;
    float* sm = &smem[wave][0][0];

    // ---- prologue: issue ch0 staging now; latency hides under table setup ----
#pragma unroll
    for (int k = 0; k < NIT; ++k) async_stage(fbase + g_off[k], sm + k * 64);

    // ---- per-lane sample tables: LDS offsets + pre-multiplied weights ----
    int cell = (lane < NCELL) ? lane : (NCELL - 1);
    int py = cell / POOL, px = cell % POOL;
    int loff0[4], loff1[4];
    float w00[4], w01[4], w10[4], w11[4];
#pragma unroll
    for (int s = 0; s < 4; ++s) {
        int sy = s >> 1, sx = s & 1;
        float y = y1 + bin_h * ((float)py + ((float)sy + 0.5f) * 0.5f);
        float x = x1 + bin_w * ((float)px + ((float)sx + 0.5f) * 0.5f);
        bool v = (y > -1.f) && (y < (float)W) && (x > -1.f) && (x < (float)W);
        float yc = fminf(fmaxf(y, 0.f), (float)(W - 1));
        float xc = fminf(fmaxf(x, 0.f), (float)(W - 1));
        int ylo = (int)floorf(yc), xlo = (int)floorf(xc);
        int yhi = min(ylo + 1, W - 1);
        float fy = yc - (float)ylo, fx = xc - (float)xlo;
        float vv = v ? 0.25f : 0.f;            // validity + 1/(SR*SR)
        int bxp = min(xlo, W - 2);             // keep float-pair in-row
        bool in = (xlo == bxp);
        float wx0 = in ? (1.f - fx) : 0.f;
        float wx1 = in ? fx : 1.f;
        float wr0 = (1.f - fy) * vv, wr1 = fy * vv;
        loff0[s] = (ylo - y0) * ww + (bxp - x0);
        loff1[s] = (yhi - y0) * ww + (bxp - x0);
        w00[s] = wr0 * wx0; w01[s] = wr0 * wx1;
        w10[s] = wr1 * wx0; w11[s] = wr1 * wx1;
    }

    // ---- channel sweep: async double-buffer, counted vmcnt, no barriers ----
    // Steady-state queue at the wait: [loads_i x10, store_{i-1}, loads_{i+1} x10].
    // Loads retire in order, so vmcnt(10) guarantees loads_i (and the store)
    // are done while loads_{i+1} remain in flight. Last iter drains with vmcnt(0).
    size_t obase = (size_t)n * NCH * NCELL + (size_t)ch0 * NCELL + cell;
#pragma unroll
    for (int i = 0; i < CHPW; ++i) {
        if (i + 1 < CHPW) {
            const float* fc = fbase + (size_t)(i + 1) * HW;
            float* nb = sm + ((i + 1) & 1) * LDSF;
#pragma unroll
            for (int k = 0; k < NIT; ++k) async_stage(fc + g_off[k], nb + k * 64);
            asm volatile("s_waitcnt vmcnt(10)" ::: "memory");
        } else {
            asm volatile("s_waitcnt vmcnt(0)" ::: "memory");
        }
        const float* cb = sm + (i & 1) * LDSF;
        float acc = 0.f;
#pragma unroll
        for (int s = 0; s < 4; ++s) {
            float a0 = cb[loff0[s]], a1 = cb[loff0[s] + 1];
            float b0 = cb[loff1[s]], b1 = cb[loff1[s] + 1];
            acc += w00[s] * a0 + w01[s] * a1 + w10[s] * b0 + w11[s] * b1;
        }
        if (lane < NCELL)
            __builtin_nontemporal_store(acc, out + obase + (size_t)i * NCELL);
    }
}

extern "C" void kernel_launch(void* const* d_in, const int* in_sizes, int n_in,
                              void* d_out, int out_size, void* d_ws, size_t ws_size,
                              hipStream_t stream) {
    const float* p2    = (const float*)d_in[0];
    const float* p3    = (const float*)d_in[1];
    const float* p4    = (const float*)d_in[2];
    const float* p5    = (const float*)d_in[3];
    const float* boxes = (const float*)d_in[4];
    const int*   bidx  = (const int*)d_in[5];
    float* out = (float*)d_out;
    int N = in_sizes[5];
    dim3 grid(CH_SPLIT, N);
    roi_align_fpn_kernel<<<grid, 256, 0, stream>>>(p2, p3, p4, p5, boxes, bidx, out, N);
}